// Round 4
// baseline (4972.298 us; speedup 1.0000x reference)
//
#include <hip/hip_runtime.h>

#define B_ 1024
#define L_ 80
#define E_ 256
#define D_ 256
#define T_ 20
#define NS_ 4
#define NSYM_ 100
#define NBLK_ 256

typedef __attribute__((ext_vector_type(8))) short short8;
typedef __attribute__((ext_vector_type(4))) float f32x4;
typedef unsigned int uint;

__device__ inline short f2b(float f) {
    unsigned u = __float_as_uint(f);
    unsigned r = (u + 0x7fffu + ((u >> 16) & 1u)) >> 16;
    return (short)r;
}
__device__ inline float b2f(short s) {
    return __uint_as_float(((unsigned)(unsigned short)s) << 16);
}
__device__ inline float fast_sigmoid(float x) { return 1.f / (1.f + __expf(-x)); }
__device__ inline float fast_tanh(float x) {
    x = fminf(fmaxf(x, -15.f), 15.f);
    float e = __expf(2.f * x);
    return (e - 1.f) / (e + 1.f);
}

// ---------------- grid barrier: distributed flag array ----------------
// R3's single fetch_add serialized 256 cross-XCD RMWs (~200ns each = ~52us).
// Here: each block release-stores its epoch to its OWN 64B-spaced flag
// (parallel), block 0 polls all 256 flags with 256 threads (parallel reads),
// then releases gen; others poll gen. No serialized RMW anywhere.
__device__ __forceinline__ void gbar(unsigned* flags, unsigned* gen, unsigned target) {
    __syncthreads();
    int g = blockIdx.x, t = threadIdx.x;
    if (g == 0) {
        if (t > 0) {
            unsigned* f = flags + t * 16;
            long spins = 0;
            while (__hip_atomic_load(f, __ATOMIC_ACQUIRE, __HIP_MEMORY_SCOPE_AGENT) < target) {
                __builtin_amdgcn_s_sleep(1);
                if (++spins > 50000000L) break;   // fail-safe: never hang
            }
        }
        __syncthreads();
        if (t == 0) {
            __threadfence();
            __hip_atomic_store(gen, target, __ATOMIC_RELEASE, __HIP_MEMORY_SCOPE_AGENT);
        }
    } else if (t == 0) {
        __threadfence();
        __hip_atomic_store(flags + g * 16, target, __ATOMIC_RELEASE, __HIP_MEMORY_SCOPE_AGENT);
        long spins = 0;
        while (__hip_atomic_load(gen, __ATOMIC_ACQUIRE, __HIP_MEMORY_SCOPE_AGENT) < target) {
            __builtin_amdgcn_s_sleep(1);
            if (++spins > 50000000L) break;
        }
    }
    __syncthreads();
}

// ---------------- init / conversion kernels ----------------

__global__ void zero_k(unsigned* __restrict__ p, size_t n) {
    size_t i = (size_t)blockIdx.x * blockDim.x + threadIdx.x;
    size_t stride = (size_t)gridDim.x * blockDim.x;
    for (; i < n; i += stride) p[i] = 0u;
}

__global__ void f2b4_k(const float* __restrict__ src, short* __restrict__ dst, size_t n4) {
    size_t i = (size_t)blockIdx.x * blockDim.x + threadIdx.x;
    size_t stride = (size_t)gridDim.x * blockDim.x;
    for (; i < n4; i += stride) {
        float4 v = ((const float4*)src)[i];
        short4 o;
        o.x = f2b(v.x); o.y = f2b(v.y); o.z = f2b(v.z); o.w = f2b(v.w);
        ((short4*)dst)[i] = o;
    }
}

__global__ void split_k(const float* __restrict__ Wsrc, short* __restrict__ dstE,
                        short* __restrict__ dstH, int rows) {
    int id = blockIdx.x * 256 + threadIdx.x;
    if (id >= rows * 512) return;
    int rr = id >> 9, cc = id & 511;
    short v = f2b(Wsrc[id]);
    if (cc < 256) dstE[rr * 256 + cc] = v;
    else          dstH[rr * 256 + (cc - 256)] = v;
}

__global__ void gatesW_k(const float* __restrict__ Wih, const float* __restrict__ Whh,
                         const float* __restrict__ bih, const float* __restrict__ bhh,
                         short* __restrict__ WgB, float* __restrict__ bg) {
    int id = blockIdx.x * 256 + threadIdx.x;
    int np = id >> 9, cc = id & 511;
    int u = np >> 2, g = np & 3;
    int srow = g * 256 + u;
    float v = (cc < 256) ? Wih[srow * 256 + cc] : Whh[srow * 256 + (cc - 256)];
    WgB[id] = f2b(v);
    if (id < 1024) {
        int u2 = id >> 2, g2 = id & 3;
        bg[id] = bih[g2 * 256 + u2] + bhh[g2 * 256 + u2];
    }
}

__global__ void embed_k(const int* __restrict__ tsi, const float* __restrict__ common,
                        const float* __restrict__ syms, short* __restrict__ embB) {
    size_t id = (size_t)blockIdx.x * 256 + threadIdx.x;
    int d = (int)(id & 255);
    size_t r = id >> 8;
    int tt = (int)(r >> 10);
    int b  = (int)(r & 1023);
    int idx = tsi[b * T_ + tt];
    float v;
    if (idx < NS_) {
        int i2 = idx < 0 ? 0 : idx;
        v = common[i2 * D_ + d];
    } else {
        int i2 = idx - NS_;
        if (i2 > NSYM_ - 1) i2 = NSYM_ - 1;
        v = syms[((size_t)b * NSYM_ + i2) * D_ + d];
    }
    embB[id] = f2b(v);
}

// generic bf16 GEMM used only for the T-batched precompute (awE, combE)
__global__ __launch_bounds__(256) void gemm_k(
    const short* __restrict__ A, int lda,
    const short* __restrict__ W,
    float* __restrict__ outF, int ldoF,
    int M, int N, int K)
{
    __shared__ alignas(16) short As[64][40];
    __shared__ alignas(16) short Ws[64][40];
    int m0 = blockIdx.x * 64, n0 = blockIdx.y * 64;
    int t = threadIdx.x;
    int w = t >> 6, l = t & 63, quad = l >> 4, lm = l & 15;
    int wm = (w >> 1) * 32, wn = (w & 1) * 32;
    f32x4 acc[2][2] = {};
    int rowL = t >> 2, c8 = (t & 3) * 8;
    for (int k0 = 0; k0 < K; k0 += 32) {
        uint4 av = *(const uint4*)(A + (size_t)(m0 + rowL) * lda + k0 + c8);
        uint4 wv = {0u, 0u, 0u, 0u};
        int wr = n0 + rowL;
        if (wr < N) wv = *(const uint4*)(W + (size_t)wr * K + k0 + c8);
        *(uint4*)&As[rowL][c8] = av;
        *(uint4*)&Ws[rowL][c8] = wv;
        __syncthreads();
        short8 af[2], wf[2];
        af[0] = *(const short8*)&As[wm + lm][quad * 8];
        af[1] = *(const short8*)&As[wm + 16 + lm][quad * 8];
        wf[0] = *(const short8*)&Ws[wn + lm][quad * 8];
        wf[1] = *(const short8*)&Ws[wn + 16 + lm][quad * 8];
        #pragma unroll
        for (int i = 0; i < 2; i++)
            #pragma unroll
            for (int j = 0; j < 2; j++)
                acc[i][j] = __builtin_amdgcn_mfma_f32_16x16x32_bf16(af[i], wf[j], acc[i][j], 0, 0, 0);
        __syncthreads();
    }
    #pragma unroll
    for (int i = 0; i < 2; i++)
        #pragma unroll
        for (int j = 0; j < 2; j++) {
            int col = n0 + wn + j * 16 + lm;
            if (col >= N) continue;
            #pragma unroll
            for (int r = 0; r < 4; r++) {
                int row = m0 + wm + i * 16 + quad * 4 + r;
                outF[(size_t)row * ldoF + col] = acc[i][j][r];
            }
        }
}

// ---------------- persistent decode kernel ----------------

struct GemmSh { alignas(16) short As[64][40]; alignas(16) short Ws[64][40]; float gS[64][68]; };
struct OutSh  { alignas(16) short As[32][40]; alignas(16) short Ws[256][40];
                float rmax[32][2]; float rsum[32][2]; };
struct AttnSh { float h1f[256]; float awP[2][80]; float apS[80]; float appS[2][128][2]; };
union Sh { GemmSh g; OutSh o; AttnSh a; };

struct DecArgs {
    const short* encB; const float* encF; int useEnc;
    const short* WaHB; const float* awE; const float* b_attn;
    const short* WcAB; const float* combE; const float* b_comb;
    const short* Wg0B; const float* bg0;
    const short* Wg1B; const float* bg1;
    const short* WoutB; const float* b_out;
    float* c0; float* c1; short* H1B;
    short* X0a; short* X0b; short* X1a; short* X1b;
    short* appliedB;
    unsigned* barFlags; unsigned* barGen;
    float* out;
};

__device__ __forceinline__ void attn_phase(AttnSh& S, const DecArgs& A, int tstep, int g, int t) {
    for (int r = 0; r < 4; r++) {
        int b = g * 4 + r;
        __syncthreads();                     // LDS boundary (prev phase / prev r)
        S.h1f[t] = b2f(A.H1B[(size_t)b * 256 + t]);
        __syncthreads();
        if (t < 160) {
            int seg = (t >= 80) ? 1 : 0;
            int l = t - seg * 80;
            const short8* wr = (const short8*)(A.WaHB + (size_t)l * 256 + seg * 128);
            const float* hf = &S.h1f[seg * 128];
            float acc = 0.f;
            #pragma unroll 4
            for (int k = 0; k < 16; k++) {
                short8 wv = wr[k];
                #pragma unroll
                for (int j = 0; j < 8; j++) acc += b2f(wv[j]) * hf[k * 8 + j];
            }
            S.awP[seg][l] = acc;
        }
        __syncthreads();
        if (t < 64) {
            const float* awE_b = A.awE + ((size_t)tstep * B_ + b) * 80;
            float v0 = S.awP[0][t] + S.awP[1][t] + awE_b[t] + A.b_attn[t];
            float v1 = -1e30f;
            if (t < 16) v1 = S.awP[0][64 + t] + S.awP[1][64 + t] + awE_b[64 + t] + A.b_attn[64 + t];
            float m = fmaxf(v0, v1);
            #pragma unroll
            for (int o = 32; o >= 1; o >>= 1) m = fmaxf(m, __shfl_xor(m, o));
            float e0 = __expf(v0 - m), e1 = (t < 16) ? __expf(v1 - m) : 0.f;
            float s = e0 + e1;
            #pragma unroll
            for (int o = 32; o >= 1; o >>= 1) s += __shfl_xor(s, o);
            float inv = 1.f / s;
            S.apS[t] = e0 * inv;
            if (t < 16) S.apS[64 + t] = e1 * inv;
        }
        __syncthreads();
        {
            int t2 = t & 127, lh = t >> 7;
            float a0 = 0.f, a1 = 0.f;
            if (A.useEnc) {
                const uint* ep = (const uint*)(A.encB + ((size_t)b * 80 + lh * 40) * 256) + t2;
                #pragma unroll 4
                for (int l2 = 0; l2 < 40; l2++) {
                    uint v = ep[(size_t)l2 * 128];
                    float w = S.apS[lh * 40 + l2];
                    a0 += w * b2f((short)(v & 0xffff));
                    a1 += w * b2f((short)(v >> 16));
                }
            } else {
                const float* ep = A.encF + ((size_t)b * 80 + lh * 40) * 256 + 2 * t2;
                #pragma unroll 4
                for (int l2 = 0; l2 < 40; l2++) {
                    float w = S.apS[lh * 40 + l2];
                    a0 += w * ep[(size_t)l2 * 256];
                    a1 += w * ep[(size_t)l2 * 256 + 1];
                }
            }
            S.appS[lh][t2][0] = a0; S.appS[lh][t2][1] = a1;
        }
        __syncthreads();
        {
            float v = S.appS[0][t >> 1][t & 1] + S.appS[1][t >> 1][t & 1];
            A.appliedB[(size_t)b * 256 + t] = f2b(v);
        }
    }
}

__device__ __forceinline__ void comb_phase(GemmSh& S, const DecArgs& A, int tstep, int g, int t,
                                           short* X0p) {
    int m0 = (g >> 2) * 64, n0 = (g & 3) * 64;
    int w = t >> 6, l = t & 63, quad = l >> 4, lm = l & 15;
    int wm = (w >> 1) * 32, wn = (w & 1) * 32;
    f32x4 acc[2][2] = {};
    int rowL = t >> 2, c8 = (t & 3) * 8;
    for (int k0 = 0; k0 < 256; k0 += 32) {
        *(uint4*)&S.As[rowL][c8] = *(const uint4*)(A.appliedB + (size_t)(m0 + rowL) * 256 + k0 + c8);
        *(uint4*)&S.Ws[rowL][c8] = *(const uint4*)(A.WcAB + (size_t)(n0 + rowL) * 256 + k0 + c8);
        __syncthreads();
        short8 af[2], wf[2];
        af[0] = *(const short8*)&S.As[wm + lm][quad * 8];
        af[1] = *(const short8*)&S.As[wm + 16 + lm][quad * 8];
        wf[0] = *(const short8*)&S.Ws[wn + lm][quad * 8];
        wf[1] = *(const short8*)&S.Ws[wn + 16 + lm][quad * 8];
        #pragma unroll
        for (int i = 0; i < 2; i++)
            #pragma unroll
            for (int j = 0; j < 2; j++)
                acc[i][j] = __builtin_amdgcn_mfma_f32_16x16x32_bf16(af[i], wf[j], acc[i][j], 0, 0, 0);
        __syncthreads();
    }
    const float* combE_t = A.combE + (size_t)tstep * B_ * 256;
    #pragma unroll
    for (int i = 0; i < 2; i++)
        #pragma unroll
        for (int j = 0; j < 2; j++) {
            int col = n0 + wn + j * 16 + lm;
            float bval = A.b_comb[col];
            #pragma unroll
            for (int r = 0; r < 4; r++) {
                int row = m0 + wm + i * 16 + quad * 4 + r;
                float v = acc[i][j][r] + bval + combE_t[(size_t)row * 256 + col];
                X0p[(size_t)row * 512 + col] = f2b(fmaxf(v, 0.f));
            }
        }
}

__device__ __forceinline__ void gates_phase(GemmSh& S, const short* X, const short* Wg,
                                            const float* bg, float* c,
                                            short* hA, int ldA, int offA,
                                            short* hB2, int ldB2, int offB2, int g, int t) {
    int m0 = (g >> 4) * 64, n0 = (g & 15) * 64;
    int w = t >> 6, l = t & 63, quad = l >> 4, lm = l & 15;
    int wm = (w >> 1) * 32, wn = (w & 1) * 32;
    f32x4 acc[2][2] = {};
    int rowL = t >> 2, c8 = (t & 3) * 8;
    for (int k0 = 0; k0 < 512; k0 += 32) {
        *(uint4*)&S.As[rowL][c8] = *(const uint4*)(X + (size_t)(m0 + rowL) * 512 + k0 + c8);
        *(uint4*)&S.Ws[rowL][c8] = *(const uint4*)(Wg + (size_t)(n0 + rowL) * 512 + k0 + c8);
        __syncthreads();
        short8 af[2], wf[2];
        af[0] = *(const short8*)&S.As[wm + lm][quad * 8];
        af[1] = *(const short8*)&S.As[wm + 16 + lm][quad * 8];
        wf[0] = *(const short8*)&S.Ws[wn + lm][quad * 8];
        wf[1] = *(const short8*)&S.Ws[wn + 16 + lm][quad * 8];
        #pragma unroll
        for (int i = 0; i < 2; i++)
            #pragma unroll
            for (int j = 0; j < 2; j++)
                acc[i][j] = __builtin_amdgcn_mfma_f32_16x16x32_bf16(af[i], wf[j], acc[i][j], 0, 0, 0);
        __syncthreads();
    }
    #pragma unroll
    for (int i = 0; i < 2; i++)
        #pragma unroll
        for (int j = 0; j < 2; j++) {
            int col = wn + j * 16 + lm;
            float bval = bg[n0 + col];
            #pragma unroll
            for (int r = 0; r < 4; r++)
                S.gS[wm + i * 16 + quad * 4 + r][col] = acc[i][j][r] + bval;
        }
    __syncthreads();
    int U0 = n0 >> 2;
    for (int item = t; item < 1024; item += 256) {
        int ml = item >> 4, ul = item & 15;
        float iv = S.gS[ml][ul * 4 + 0];
        float fv = S.gS[ml][ul * 4 + 1];
        float gv = S.gS[ml][ul * 4 + 2];
        float ov = S.gS[ml][ul * 4 + 3];
        float si = fast_sigmoid(iv);
        float sf = fast_sigmoid(fv);
        float so = fast_sigmoid(ov);
        float tg = fast_tanh(gv);
        int m = m0 + ml, u = U0 + ul;
        size_t ci = (size_t)m * 256 + u;
        float cn = sf * c[ci] + si * tg;
        float hn = so * fast_tanh(cn);
        c[ci] = cn;
        short hb = f2b(hn);
        hA[(size_t)m * ldA + offA + u] = hb;
        hB2[(size_t)m * ldB2 + offB2 + u] = hb;
    }
}

// out GEMM + log-softmax, logits register-resident (g in [0,32))
__device__ __forceinline__ void out_phase(OutSh& S, const DecArgs& A, int tstep, int g, int t) {
    int m0 = g * 32;
    int w = t >> 6, l = t & 63, quad = l >> 4, lm = l & 15;
    int wm = (w >> 1) * 16, wn = (w & 1) * 128;
    f32x4 acc[8] = {};
    for (int k0 = 0; k0 < 256; k0 += 32) {
        if (t < 128) {
            int rr = t >> 2, cc = (t & 3) * 8;
            *(uint4*)&S.As[rr][cc] = *(const uint4*)(A.H1B + (size_t)(m0 + rr) * 256 + k0 + cc);
        }
        for (int cch = t; cch < 1024; cch += 256) {
            int rr = cch >> 2, cc = (cch & 3) * 8;
            *(uint4*)&S.Ws[rr][cc] = *(const uint4*)(A.WoutB + (size_t)rr * 256 + k0 + cc);
        }
        __syncthreads();
        short8 af = *(const short8*)&S.As[wm + lm][quad * 8];
        #pragma unroll
        for (int j = 0; j < 8; j++) {
            short8 wf = *(const short8*)&S.Ws[wn + j * 16 + lm][quad * 8];
            acc[j] = __builtin_amdgcn_mfma_f32_16x16x32_bf16(af, wf, acc[j], 0, 0, 0);
        }
        __syncthreads();
    }
    #pragma unroll
    for (int j = 0; j < 8; j++) {
        float bv = A.b_out[wn + j * 16 + lm];
        #pragma unroll
        for (int r = 0; r < 4; r++) acc[j][r] += bv;
    }
    float mx4[4];
    #pragma unroll
    for (int r = 0; r < 4; r++) {
        float m = acc[0][r];
        #pragma unroll
        for (int j = 1; j < 8; j++) m = fmaxf(m, acc[j][r]);
        #pragma unroll
        for (int o = 1; o < 16; o <<= 1) m = fmaxf(m, __shfl_xor(m, o));
        mx4[r] = m;
    }
    if (lm == 0) {
        #pragma unroll
        for (int r = 0; r < 4; r++) S.rmax[wm + quad * 4 + r][w & 1] = mx4[r];
    }
    __syncthreads();
    float gmax[4], sum4[4];
    #pragma unroll
    for (int r = 0; r < 4; r++) {
        int row = wm + quad * 4 + r;
        gmax[r] = fmaxf(S.rmax[row][0], S.rmax[row][1]);
        float s = 0.f;
        #pragma unroll
        for (int j = 0; j < 8; j++) s += __expf(acc[j][r] - gmax[r]);
        #pragma unroll
        for (int o = 1; o < 16; o <<= 1) s += __shfl_xor(s, o);
        sum4[r] = s;
    }
    if (lm == 0) {
        #pragma unroll
        for (int r = 0; r < 4; r++) S.rsum[wm + quad * 4 + r][w & 1] = sum4[r];
    }
    __syncthreads();
    float* outp = A.out + (size_t)tstep * B_ * 256;
    #pragma unroll
    for (int r = 0; r < 4; r++) {
        int row = wm + quad * 4 + r;
        float lg = gmax[r] + __logf(S.rsum[row][0] + S.rsum[row][1]);
        float* orow = outp + (size_t)(m0 + row) * 256 + wn + lm;
        #pragma unroll
        for (int j = 0; j < 8; j++) orow[j * 16] = acc[j][r] - lg;
    }
    __syncthreads();
}

__global__ __launch_bounds__(256) void decode_k(DecArgs A) {
    __shared__ Sh sh;
    int g = blockIdx.x, t = threadIdx.x;
    unsigned bt = 0;
    for (int ts = 0; ts < T_; ts++) {
        int p = ts & 1;
        short* X0p = p ? A.X0b : A.X0a;
        short* X0q = p ? A.X0a : A.X0b;
        short* X1p = p ? A.X1b : A.X1a;
        short* X1q = p ? A.X1a : A.X1b;

        attn_phase(sh.a, A, ts, g, t);
        gbar(A.barFlags, A.barGen, ++bt);
        // comb on blocks 0..63; out(ts-1) on blocks 64..95 (H1B still holds h1(ts-1))
        if (g < 64) comb_phase(sh.g, A, ts, g, t, X0p);
        else if (g < 96 && ts > 0) out_phase(sh.o, A, ts - 1, g - 64, t);
        gbar(A.barFlags, A.barGen, ++bt);
        gates_phase(sh.g, X0p, A.Wg0B, A.bg0, A.c0, X0q, 512, 256, X1p, 512, 0, g, t);
        gbar(A.barFlags, A.barGen, ++bt);
        gates_phase(sh.g, X1p, A.Wg1B, A.bg1, A.c1, X1q, 512, 256, A.H1B, 256, 0, g, t);
        gbar(A.barFlags, A.barGen, ++bt);
    }
    if (g >= 64 && g < 96) out_phase(sh.o, A, T_ - 1, g - 64, t);
}

// ---------------- host ----------------

extern "C" void kernel_launch(void* const* d_in, const int* in_sizes, int n_in,
                              void* d_out, int out_size, void* d_ws, size_t ws_size,
                              hipStream_t stream) {
    const float* encF    = (const float*)d_in[0];
    const float* syms    = (const float*)d_in[1];
    const int*   tsi     = (const int*)d_in[2];
    const float* commonE = (const float*)d_in[3];
    const float* W_attn  = (const float*)d_in[4];
    const float* b_attn  = (const float*)d_in[5];
    const float* W_comb  = (const float*)d_in[6];
    const float* b_comb  = (const float*)d_in[7];
    const float* Wih0    = (const float*)d_in[8];
    const float* Whh0    = (const float*)d_in[9];
    const float* bih0    = (const float*)d_in[10];
    const float* bhh0    = (const float*)d_in[11];
    const float* Wih1    = (const float*)d_in[12];
    const float* Whh1    = (const float*)d_in[13];
    const float* bih1    = (const float*)d_in[14];
    const float* bhh1    = (const float*)d_in[15];
    const float* W_out   = (const float*)d_in[16];
    const float* b_out   = (const float*)d_in[17];
    float* out = (float*)d_out;

    char* base = (char*)d_ws;
    size_t off = 0;
    auto alloc = [&](size_t bytes) -> char* {
        char* p = base + off;
        off += (bytes + 255) & ~(size_t)255;
        return p;
    };
    // zero-region first (contiguous): barrier state, c0, c1, H1B, X0a, X1a
    unsigned* barGen   = (unsigned*)alloc(256);
    unsigned* barFlags = (unsigned*)alloc(NBLK_ * 16 * 4);
    float* c0  = (float*)alloc((size_t)B_ * D_ * 4);
    float* c1  = (float*)alloc((size_t)B_ * D_ * 4);
    short* H1B = (short*)alloc((size_t)B_ * D_ * 2);
    short* X0a = (short*)alloc((size_t)B_ * 512 * 2);
    short* X1a = (short*)alloc((size_t)B_ * 512 * 2);
    size_t zeroBytes = off;
    short* X0b = (short*)alloc((size_t)B_ * 512 * 2);
    short* X1b = (short*)alloc((size_t)B_ * 512 * 2);
    short* appliedB = (short*)alloc((size_t)B_ * E_ * 2);
    float* awE   = (float*)alloc((size_t)T_ * B_ * L_ * 4);
    float* combE = (float*)alloc((size_t)T_ * B_ * D_ * 4);
    short* embB  = (short*)alloc((size_t)T_ * B_ * D_ * 2);
    short* WaEB  = (short*)alloc((size_t)L_ * D_ * 2);
    short* WaHB  = (short*)alloc((size_t)L_ * D_ * 2);
    short* WcEB  = (short*)alloc((size_t)D_ * D_ * 2);
    short* WcAB  = (short*)alloc((size_t)D_ * E_ * 2);
    short* Wg0B  = (short*)alloc((size_t)1024 * 512 * 2);
    short* Wg1B  = (short*)alloc((size_t)1024 * 512 * 2);
    short* WoutB = (short*)alloc((size_t)D_ * E_ * 2);
    float* bg0 = (float*)alloc(1024 * 4);
    float* bg1 = (float*)alloc(1024 * 4);
    short* encB = (short*)alloc((size_t)B_ * L_ * E_ * 2);
    int useEnc = (off <= ws_size) ? 1 : 0;

    zero_k<<<2048, 256, 0, stream>>>((unsigned*)base, zeroBytes / 4);
    if (useEnc)
        f2b4_k<<<4096, 256, 0, stream>>>(encF, encB, (size_t)B_ * L_ * E_ / 4);
    f2b4_k<<<64, 256, 0, stream>>>(W_out, WoutB, (size_t)D_ * E_ / 4);
    split_k<<<(80 * 512) / 256, 256, 0, stream>>>(W_attn, WaEB, WaHB, 80);
    split_k<<<(256 * 512) / 256, 256, 0, stream>>>(W_comb, WcEB, WcAB, 256);
    gatesW_k<<<2048, 256, 0, stream>>>(Wih0, Whh0, bih0, bhh0, Wg0B, bg0);
    gatesW_k<<<2048, 256, 0, stream>>>(Wih1, Whh1, bih1, bhh1, Wg1B, bg1);
    embed_k<<<(T_ * B_ * D_) / 256, 256, 0, stream>>>(tsi, commonE, syms, embB);
    gemm_k<<<dim3(320, 2), 256, 0, stream>>>(embB, 256, WaEB, awE, 80, 20480, 80, 256);
    gemm_k<<<dim3(320, 4), 256, 0, stream>>>(embB, 256, WcEB, combE, 256, 20480, 256, 256);

    DecArgs da;
    da.encB = encB; da.encF = encF; da.useEnc = useEnc;
    da.WaHB = WaHB; da.awE = awE; da.b_attn = b_attn;
    da.WcAB = WcAB; da.combE = combE; da.b_comb = b_comb;
    da.Wg0B = Wg0B; da.bg0 = bg0;
    da.Wg1B = Wg1B; da.bg1 = bg1;
    da.WoutB = WoutB; da.b_out = b_out;
    da.c0 = c0; da.c1 = c1; da.H1B = H1B;
    da.X0a = X0a; da.X0b = X0b; da.X1a = X1a; da.X1b = X1b;
    da.appliedB = appliedB;
    da.barFlags = barFlags; da.barGen = barGen;
    da.out = out;
    decode_k<<<NBLK_, 256, 0, stream>>>(da);
}

// Round 5
// 2006.484 us; speedup vs baseline: 2.4781x; 2.4781x over previous
//
#include <hip/hip_runtime.h>

#define B_ 1024
#define L_ 80
#define E_ 256
#define D_ 256
#define T_ 20
#define NS_ 4
#define NSYM_ 100
#define NBLK_ 256
#define SMEM_SZ 152576

typedef __attribute__((ext_vector_type(8))) short short8;
typedef __attribute__((ext_vector_type(4))) float f32x4;
typedef __attribute__((ext_vector_type(4))) unsigned int u32x4;
typedef unsigned int uint;

__device__ inline short f2b(float f) {
    unsigned u = __float_as_uint(f);
    unsigned r = (u + 0x7fffu + ((u >> 16) & 1u)) >> 16;
    return (short)r;
}
__device__ inline float b2f(short s) {
    return __uint_as_float(((unsigned)(unsigned short)s) << 16);
}
__device__ inline float fast_sigmoid(float x) { return 1.f / (1.f + __expf(-x)); }
__device__ inline float fast_tanh(float x) {
    x = fminf(fmaxf(x, -15.f), 15.f);
    float e = __expf(2.f * x);
    return (e - 1.f) / (e + 1.f);
}

// L2-bypass 16B load (sc0 sc1): reads the device coherence point, so no
// acquire fence / buffer_inv is needed anywhere (keeps weights L2-hot).
__device__ __forceinline__ u32x4 gload_sc(const void* p) {
    u32x4 d;
    asm volatile("global_load_dwordx4 %0, %1, off sc0 sc1"
                 : "=v"(d) : "v"(p) : "memory");
    return d;
}
__device__ __forceinline__ void vmwait0() {
    asm volatile("s_waitcnt vmcnt(0)" ::: "memory");
}

// ---------------- grid barrier: relaxed polls, release publish ----------------
__device__ __forceinline__ void gbar(unsigned* flags, unsigned* gen, unsigned target) {
    __syncthreads();
    int g = blockIdx.x, t = threadIdx.x;
    if (g == 0) {
        if (t > 0) {
            unsigned* f = flags + t * 16;
            long spins = 0;
            while (__hip_atomic_load(f, __ATOMIC_RELAXED, __HIP_MEMORY_SCOPE_AGENT) < target) {
                __builtin_amdgcn_s_sleep(1);
                if (++spins > 30000000L) break;   // fail-safe: never hang the harness
            }
        }
        __syncthreads();
        if (t == 0)  // RELEASE: vmcnt(0)+wbl2 publishes this XCD's phase writes
            __hip_atomic_store(gen, target, __ATOMIC_RELEASE, __HIP_MEMORY_SCOPE_AGENT);
    } else if (t == 0) {
        __hip_atomic_store(flags + g * 16, target, __ATOMIC_RELEASE, __HIP_MEMORY_SCOPE_AGENT);
        long spins = 0;
        while (__hip_atomic_load(gen, __ATOMIC_RELAXED, __HIP_MEMORY_SCOPE_AGENT) < target) {
            __builtin_amdgcn_s_sleep(1);
            if (++spins > 30000000L) break;
        }
    }
    __syncthreads();
}

// ---------------- init / conversion kernels ----------------

__global__ void zero_k(unsigned* __restrict__ p, size_t n) {
    size_t i = (size_t)blockIdx.x * blockDim.x + threadIdx.x;
    size_t stride = (size_t)gridDim.x * blockDim.x;
    for (; i < n; i += stride) p[i] = 0u;
}

__global__ void f2b4_k(const float* __restrict__ src, short* __restrict__ dst, size_t n4) {
    size_t i = (size_t)blockIdx.x * blockDim.x + threadIdx.x;
    size_t stride = (size_t)gridDim.x * blockDim.x;
    for (; i < n4; i += stride) {
        float4 v = ((const float4*)src)[i];
        short4 o;
        o.x = f2b(v.x); o.y = f2b(v.y); o.z = f2b(v.z); o.w = f2b(v.w);
        ((short4*)dst)[i] = o;
    }
}

__global__ void split_k(const float* __restrict__ Wsrc, short* __restrict__ dstE,
                        short* __restrict__ dstH, int rows) {
    int id = blockIdx.x * 256 + threadIdx.x;
    if (id >= rows * 512) return;
    int rr = id >> 9, cc = id & 511;
    short v = f2b(Wsrc[id]);
    if (cc < 256) dstE[rr * 256 + cc] = v;
    else          dstH[rr * 256 + (cc - 256)] = v;
}

__global__ void gatesW_k(const float* __restrict__ Wih, const float* __restrict__ Whh,
                         const float* __restrict__ bih, const float* __restrict__ bhh,
                         short* __restrict__ WgB, float* __restrict__ bg) {
    int id = blockIdx.x * 256 + threadIdx.x;
    int np = id >> 9, cc = id & 511;
    int u = np >> 2, g = np & 3;
    int srow = g * 256 + u;
    float v = (cc < 256) ? Wih[srow * 256 + cc] : Whh[srow * 256 + (cc - 256)];
    WgB[id] = f2b(v);
    if (id < 1024) {
        int u2 = id >> 2, g2 = id & 3;
        bg[id] = bih[g2 * 256 + u2] + bhh[g2 * 256 + u2];
    }
}

__global__ void embed_k(const int* __restrict__ tsi, const float* __restrict__ common,
                        const float* __restrict__ syms, short* __restrict__ embB) {
    size_t id = (size_t)blockIdx.x * 256 + threadIdx.x;
    int d = (int)(id & 255);
    size_t r = id >> 8;
    int tt = (int)(r >> 10);
    int b  = (int)(r & 1023);
    int idx = tsi[b * T_ + tt];
    float v;
    if (idx < NS_) {
        int i2 = idx < 0 ? 0 : idx;
        v = common[i2 * D_ + d];
    } else {
        int i2 = idx - NS_;
        if (i2 > NSYM_ - 1) i2 = NSYM_ - 1;
        v = syms[((size_t)b * NSYM_ + i2) * D_ + d];
    }
    embB[id] = f2b(v);
}

// generic bf16 GEMM used only for the T-batched precompute (awE, combE)
__global__ __launch_bounds__(256) void gemm_k(
    const short* __restrict__ A, int lda,
    const short* __restrict__ W,
    float* __restrict__ outF, int ldoF,
    int M, int N, int K)
{
    __shared__ alignas(16) short As[64][40];
    __shared__ alignas(16) short Ws[64][40];
    int m0 = blockIdx.x * 64, n0 = blockIdx.y * 64;
    int t = threadIdx.x;
    int w = t >> 6, l = t & 63, quad = l >> 4, lm = l & 15;
    int wm = (w >> 1) * 32, wn = (w & 1) * 32;
    f32x4 acc[2][2] = {};
    int rowL = t >> 2, c8 = (t & 3) * 8;
    for (int k0 = 0; k0 < K; k0 += 32) {
        uint4 av = *(const uint4*)(A + (size_t)(m0 + rowL) * lda + k0 + c8);
        uint4 wv = {0u, 0u, 0u, 0u};
        int wr = n0 + rowL;
        if (wr < N) wv = *(const uint4*)(W + (size_t)wr * K + k0 + c8);
        *(uint4*)&As[rowL][c8] = av;
        *(uint4*)&Ws[rowL][c8] = wv;
        __syncthreads();
        short8 af[2], wf[2];
        af[0] = *(const short8*)&As[wm + lm][quad * 8];
        af[1] = *(const short8*)&As[wm + 16 + lm][quad * 8];
        wf[0] = *(const short8*)&Ws[wn + lm][quad * 8];
        wf[1] = *(const short8*)&Ws[wn + 16 + lm][quad * 8];
        #pragma unroll
        for (int i = 0; i < 2; i++)
            #pragma unroll
            for (int j = 0; j < 2; j++)
                acc[i][j] = __builtin_amdgcn_mfma_f32_16x16x32_bf16(af[i], wf[j], acc[i][j], 0, 0, 0);
        __syncthreads();
    }
    #pragma unroll
    for (int i = 0; i < 2; i++)
        #pragma unroll
        for (int j = 0; j < 2; j++) {
            int col = n0 + wn + j * 16 + lm;
            if (col >= N) continue;
            #pragma unroll
            for (int r = 0; r < 4; r++) {
                int row = m0 + wm + i * 16 + quad * 4 + r;
                outF[(size_t)row * ldoF + col] = acc[i][j][r];
            }
        }
}

// ---------------- persistent decode kernel ----------------

struct DecArgs {
    const short* encB; const float* encF; int useEnc;
    const short* WaHB; const float* awE; const float* b_attn;
    const short* WcAB; const float* combE; const float* b_comb;
    const short* Wg0B; const float* bg0;
    const short* Wg1B; const float* bg1;
    const short* WoutB; const float* b_out;
    float* c0; float* c1; short* H1B;
    short* X0a; short* X0b; short* X1a; short* X1b;
    short* appliedB;
    unsigned* barFlags; unsigned* barGen;
    float* out;
};

__device__ __forceinline__ void attn_phase(char* smem, const DecArgs& A, int tstep, int g, int t) {
    float (*h1f)[264]     = (float(*)[264])smem;                 // 4224 B
    float (*awP)[80]      = (float(*)[80])(smem + 4224);         // 640 B
    float* apS            = (float*)(smem + 4864);               // 320 B
    float (*appS)[128][2] = (float(*)[128][2])(smem + 5184);     // 2048 B

    // bypass-prefetch h1 (mutable shared) for all 4 batch rows of this block
    if (t < 128) {
        int r = t >> 5, ch = t & 31;
        u32x4 v = gload_sc(A.H1B + ((size_t)(g * 4 + r) * 256) + ch * 8);
        vmwait0();
        #pragma unroll
        for (int j = 0; j < 4; j++) {
            uint u = v[j];
            h1f[r][ch * 8 + 2 * j]     = b2f((short)(u & 0xffff));
            h1f[r][ch * 8 + 2 * j + 1] = b2f((short)(u >> 16));
        }
    }
    __syncthreads();

    for (int r = 0; r < 4; r++) {
        int b = g * 4 + r;
        if (t < 160) {
            int seg = (t >= 80) ? 1 : 0;
            int l = t - seg * 80;
            const short8* wr = (const short8*)(A.WaHB + (size_t)l * 256 + seg * 128);
            const float* hf = &h1f[r][seg * 128];
            float acc = 0.f;
            #pragma unroll 4
            for (int k = 0; k < 16; k++) {
                short8 wv = wr[k];
                #pragma unroll
                for (int j = 0; j < 8; j++) acc += b2f(wv[j]) * hf[k * 8 + j];
            }
            awP[seg][l] = acc;
        }
        __syncthreads();
        if (t < 64) {
            const float* awE_b = A.awE + ((size_t)tstep * B_ + b) * 80;
            float v0 = awP[0][t] + awP[1][t] + awE_b[t] + A.b_attn[t];
            float v1 = -1e30f;
            if (t < 16) v1 = awP[0][64 + t] + awP[1][64 + t] + awE_b[64 + t] + A.b_attn[64 + t];
            float m = fmaxf(v0, v1);
            #pragma unroll
            for (int o = 32; o >= 1; o >>= 1) m = fmaxf(m, __shfl_xor(m, o));
            float e0 = __expf(v0 - m), e1 = (t < 16) ? __expf(v1 - m) : 0.f;
            float s = e0 + e1;
            #pragma unroll
            for (int o = 32; o >= 1; o >>= 1) s += __shfl_xor(s, o);
            float inv = 1.f / s;
            apS[t] = e0 * inv;
            if (t < 16) apS[64 + t] = e1 * inv;
        }
        __syncthreads();
        {
            int t2 = t & 127, lh = t >> 7;
            float a0 = 0.f, a1 = 0.f;
            if (A.useEnc) {
                const uint* ep = (const uint*)(A.encB + ((size_t)b * 80 + lh * 40) * 256) + t2;
                #pragma unroll 4
                for (int l2 = 0; l2 < 40; l2++) {
                    uint v = ep[(size_t)l2 * 128];
                    float w = apS[lh * 40 + l2];
                    a0 += w * b2f((short)(v & 0xffff));
                    a1 += w * b2f((short)(v >> 16));
                }
            } else {
                const float* ep = A.encF + ((size_t)b * 80 + lh * 40) * 256 + 2 * t2;
                #pragma unroll 4
                for (int l2 = 0; l2 < 40; l2++) {
                    float w = apS[lh * 40 + l2];
                    a0 += w * ep[(size_t)l2 * 256];
                    a1 += w * ep[(size_t)l2 * 256 + 1];
                }
            }
            appS[lh][t2][0] = a0; appS[lh][t2][1] = a1;
        }
        __syncthreads();
        {
            float v = appS[0][t >> 1][t & 1] + appS[1][t >> 1][t & 1];
            A.appliedB[(size_t)b * 256 + t] = f2b(v);     // plain store; released at gbar
        }
        __syncthreads();
    }
}

// comb: A = appliedB (bypass), W = WcAB (cached). Full-tile LDS, sync-free K-loop.
__device__ __forceinline__ void comb_phase(char* smem, const DecArgs& A, int tstep, int g, int t,
                                           short* X0p) {
    short (*Xs)[264] = (short(*)[264])smem;           // 33792 B
    short (*Wf)[264] = (short(*)[264])(smem + 33792); // 33792 B
    int m0 = (g >> 2) * 64, n0 = (g & 3) * 64;
    int row = t >> 2, cbase = (t & 3) * 8;
    {
        const short* Ab = A.appliedB + (size_t)(m0 + row) * 256 + cbase;
        const short* Wb = A.WcAB + (size_t)(n0 + row) * 256 + cbase;
        u32x4 xv[8];
        #pragma unroll
        for (int i = 0; i < 8; i++) xv[i] = gload_sc(Ab + i * 32);
        vmwait0();
        #pragma unroll
        for (int i = 0; i < 8; i++) *(u32x4*)&Xs[row][cbase + i * 32] = xv[i];
        #pragma unroll
        for (int i = 0; i < 8; i++)
            *(u32x4*)&Wf[row][cbase + i * 32] = *(const u32x4*)(Wb + i * 32);
    }
    __syncthreads();
    int w = t >> 6, l = t & 63, quad = l >> 4, lm = l & 15;
    int wm = (w >> 1) * 32, wn = (w & 1) * 32;
    f32x4 acc[2][2] = {};
    #pragma unroll
    for (int k0 = 0; k0 < 256; k0 += 32) {
        short8 af0 = *(const short8*)&Xs[wm + lm][quad * 8 + k0];
        short8 af1 = *(const short8*)&Xs[wm + 16 + lm][quad * 8 + k0];
        short8 wf0 = *(const short8*)&Wf[wn + lm][quad * 8 + k0];
        short8 wf1 = *(const short8*)&Wf[wn + 16 + lm][quad * 8 + k0];
        acc[0][0] = __builtin_amdgcn_mfma_f32_16x16x32_bf16(af0, wf0, acc[0][0], 0, 0, 0);
        acc[0][1] = __builtin_amdgcn_mfma_f32_16x16x32_bf16(af0, wf1, acc[0][1], 0, 0, 0);
        acc[1][0] = __builtin_amdgcn_mfma_f32_16x16x32_bf16(af1, wf0, acc[1][0], 0, 0, 0);
        acc[1][1] = __builtin_amdgcn_mfma_f32_16x16x32_bf16(af1, wf1, acc[1][1], 0, 0, 0);
    }
    const float* combE_t = A.combE + (size_t)tstep * B_ * 256;
    #pragma unroll
    for (int i = 0; i < 2; i++)
        #pragma unroll
        for (int j = 0; j < 2; j++) {
            int col = n0 + wn + j * 16 + lm;
            float bval = A.b_comb[col];
            #pragma unroll
            for (int r = 0; r < 4; r++) {
                int rw = m0 + wm + i * 16 + quad * 4 + r;
                float v = acc[i][j][r] + bval + combE_t[(size_t)rw * 256 + col];
                X0p[(size_t)rw * 512 + col] = f2b(fmaxf(v, 0.f));
            }
        }
}

// gates: X (bypass) and Wg (cached) fully LDS-resident; sync-free K-loop.
__device__ __forceinline__ void gates_phase(char* smem, const short* X, const short* Wg,
                                            const float* bg, float* c,
                                            short* hA, int ldA, int offA,
                                            short* hB2, int ldB2, int offB2, int g, int t) {
    short (*Xs)[520] = (short(*)[520])smem;            // 66560 B
    short (*Wf)[520] = (short(*)[520])(smem + 66560);  // 66560 B
    float (*gS)[68]  = (float(*)[68])(smem + 133120);  // 17408 B
    int m0 = (g >> 4) * 64, n0 = (g & 15) * 64;
    int row = t >> 2, cbase = (t & 3) * 8;
    {
        const short* Xb = X + (size_t)(m0 + row) * 512 + cbase;
        const short* Wb = Wg + (size_t)(n0 + row) * 512 + cbase;
        u32x4 xv[16];
        #pragma unroll
        for (int i = 0; i < 16; i++) xv[i] = gload_sc(Xb + i * 32);
        vmwait0();
        #pragma unroll
        for (int i = 0; i < 16; i++) *(u32x4*)&Xs[row][cbase + i * 32] = xv[i];
        #pragma unroll
        for (int i = 0; i < 16; i++)
            *(u32x4*)&Wf[row][cbase + i * 32] = *(const u32x4*)(Wb + i * 32);
    }
    __syncthreads();
    int w = t >> 6, l = t & 63, quad = l >> 4, lm = l & 15;
    int wm = (w >> 1) * 32, wn = (w & 1) * 32;
    f32x4 acc[2][2] = {};
    #pragma unroll
    for (int k0 = 0; k0 < 512; k0 += 32) {
        short8 af0 = *(const short8*)&Xs[wm + lm][quad * 8 + k0];
        short8 af1 = *(const short8*)&Xs[wm + 16 + lm][quad * 8 + k0];
        short8 wf0 = *(const short8*)&Wf[wn + lm][quad * 8 + k0];
        short8 wf1 = *(const short8*)&Wf[wn + 16 + lm][quad * 8 + k0];
        acc[0][0] = __builtin_amdgcn_mfma_f32_16x16x32_bf16(af0, wf0, acc[0][0], 0, 0, 0);
        acc[0][1] = __builtin_amdgcn_mfma_f32_16x16x32_bf16(af0, wf1, acc[0][1], 0, 0, 0);
        acc[1][0] = __builtin_amdgcn_mfma_f32_16x16x32_bf16(af1, wf0, acc[1][0], 0, 0, 0);
        acc[1][1] = __builtin_amdgcn_mfma_f32_16x16x32_bf16(af1, wf1, acc[1][1], 0, 0, 0);
    }
    #pragma unroll
    for (int i = 0; i < 2; i++)
        #pragma unroll
        for (int j = 0; j < 2; j++) {
            int col = wn + j * 16 + lm;
            float bval = bg[n0 + col];
            #pragma unroll
            for (int r = 0; r < 4; r++)
                gS[wm + i * 16 + quad * 4 + r][col] = acc[i][j][r] + bval;
        }
    __syncthreads();
    int U0 = n0 >> 2;
    for (int item = t; item < 1024; item += 256) {
        int ml = item >> 4, ul = item & 15;
        float iv = gS[ml][ul * 4 + 0];
        float fv = gS[ml][ul * 4 + 1];
        float gv = gS[ml][ul * 4 + 2];
        float ov = gS[ml][ul * 4 + 3];
        float si = fast_sigmoid(iv);
        float sf = fast_sigmoid(fv);
        float so = fast_sigmoid(ov);
        float tg = fast_tanh(gv);
        int m = m0 + ml, u = U0 + ul;
        size_t ci = (size_t)m * 256 + u;
        float cn = sf * c[ci] + si * tg;
        float hn = so * fast_tanh(cn);
        c[ci] = cn;
        short hb = f2b(hn);
        hA[(size_t)m * ldA + offA + u] = hb;
        hB2[(size_t)m * ldB2 + offB2 + u] = hb;
    }
}

// out: H1B (bypass) + WoutB (cached) fully LDS-resident; g in [0,32)
__device__ __forceinline__ void out_phase(char* smem, const DecArgs& A, int tstep, int g, int t) {
    short (*As)[264]  = (short(*)[264])smem;             // 16896 B
    short (*WoF)[264] = (short(*)[264])(smem + 16896);   // 135168 B -> 152064
    float (*rmax)[2]  = (float(*)[2])(smem + 152064);    // 256 B
    float (*rsum)[2]  = (float(*)[2])(smem + 152320);    // 256 B -> 152576
    int m0 = g * 32;
    {
        u32x4 av[4];
        #pragma unroll
        for (int i = 0; i < 4; i++) {
            int id = i * 256 + t;
            av[i] = gload_sc(A.H1B + (size_t)(m0 + (id >> 5)) * 256 + (id & 31) * 8);
        }
        vmwait0();
        #pragma unroll
        for (int i = 0; i < 4; i++) {
            int id = i * 256 + t;
            *(u32x4*)&As[id >> 5][(id & 31) * 8] = av[i];
        }
        #pragma unroll
        for (int i = 0; i < 32; i++) {
            int id = i * 256 + t;
            *(u32x4*)&WoF[id >> 5][(id & 31) * 8] =
                *(const u32x4*)(A.WoutB + (size_t)(id >> 5) * 256 + (id & 31) * 8);
        }
    }
    __syncthreads();
    int w = t >> 6, l = t & 63, quad = l >> 4, lm = l & 15;
    int wm = (w >> 1) * 16, wn = (w & 1) * 128;
    f32x4 acc[8] = {};
    #pragma unroll
    for (int k0 = 0; k0 < 256; k0 += 32) {
        short8 af = *(const short8*)&As[wm + lm][quad * 8 + k0];
        #pragma unroll
        for (int j = 0; j < 8; j++) {
            short8 wf = *(const short8*)&WoF[wn + j * 16 + lm][quad * 8 + k0];
            acc[j] = __builtin_amdgcn_mfma_f32_16x16x32_bf16(af, wf, acc[j], 0, 0, 0);
        }
    }
    #pragma unroll
    for (int j = 0; j < 8; j++) {
        float bv = A.b_out[wn + j * 16 + lm];
        #pragma unroll
        for (int r = 0; r < 4; r++) acc[j][r] += bv;
    }
    float mx4[4];
    #pragma unroll
    for (int r = 0; r < 4; r++) {
        float m = acc[0][r];
        #pragma unroll
        for (int j = 1; j < 8; j++) m = fmaxf(m, acc[j][r]);
        #pragma unroll
        for (int o = 1; o < 16; o <<= 1) m = fmaxf(m, __shfl_xor(m, o));
        mx4[r] = m;
    }
    if (lm == 0) {
        #pragma unroll
        for (int r = 0; r < 4; r++) rmax[wm + quad * 4 + r][w & 1] = mx4[r];
    }
    __syncthreads();
    float gmax[4], sum4[4];
    #pragma unroll
    for (int r = 0; r < 4; r++) {
        int row = wm + quad * 4 + r;
        gmax[r] = fmaxf(rmax[row][0], rmax[row][1]);
        float s = 0.f;
        #pragma unroll
        for (int j = 0; j < 8; j++) s += __expf(acc[j][r] - gmax[r]);
        #pragma unroll
        for (int o = 1; o < 16; o <<= 1) s += __shfl_xor(s, o);
        sum4[r] = s;
    }
    if (lm == 0) {
        #pragma unroll
        for (int r = 0; r < 4; r++) rsum[wm + quad * 4 + r][w & 1] = sum4[r];
    }
    __syncthreads();
    float* outp = A.out + (size_t)tstep * B_ * 256;
    #pragma unroll
    for (int r = 0; r < 4; r++) {
        int row = wm + quad * 4 + r;
        float lg = gmax[r] + __logf(rsum[row][0] + rsum[row][1]);
        float* orow = outp + (size_t)(m0 + row) * 256 + wn + lm;
        #pragma unroll
        for (int j = 0; j < 8; j++) orow[j * 16] = acc[j][r] - lg;
    }
    __syncthreads();
}

__global__ __launch_bounds__(256, 1) void decode_k(DecArgs A) {
    extern __shared__ char smem[];
    int g = blockIdx.x, t = threadIdx.x;
    unsigned bt = 0;
    for (int ts = 0; ts < T_; ts++) {
        int p = ts & 1;
        short* X0p = p ? A.X0b : A.X0a;
        short* X0q = p ? A.X0a : A.X0b;
        short* X1p = p ? A.X1b : A.X1a;
        short* X1q = p ? A.X1a : A.X1b;

        attn_phase(smem, A, ts, g, t);
        gbar(A.barFlags, A.barGen, ++bt);
        // comb on blocks 0..63; out(ts-1) on blocks 64..95 (H1B still = h1(ts-1))
        if (g < 64) comb_phase(smem, A, ts, g, t, X0p);
        else if (g < 96 && ts > 0) out_phase(smem, A, ts - 1, g - 64, t);
        gbar(A.barFlags, A.barGen, ++bt);
        gates_phase(smem, X0p, A.Wg0B, A.bg0, A.c0, X0q, 512, 256, X1p, 512, 0, g, t);
        gbar(A.barFlags, A.barGen, ++bt);
        gates_phase(smem, X1p, A.Wg1B, A.bg1, A.c1, X1q, 512, 256, A.H1B, 256, 0, g, t);
        gbar(A.barFlags, A.barGen, ++bt);
    }
    if (g >= 64 && g < 96) out_phase(smem, A, T_ - 1, g - 64, t);
}

// ---------------- host ----------------

extern "C" void kernel_launch(void* const* d_in, const int* in_sizes, int n_in,
                              void* d_out, int out_size, void* d_ws, size_t ws_size,
                              hipStream_t stream) {
    const float* encF    = (const float*)d_in[0];
    const float* syms    = (const float*)d_in[1];
    const int*   tsi     = (const int*)d_in[2];
    const float* commonE = (const float*)d_in[3];
    const float* W_attn  = (const float*)d_in[4];
    const float* b_attn  = (const float*)d_in[5];
    const float* W_comb  = (const float*)d_in[6];
    const float* b_comb  = (const float*)d_in[7];
    const float* Wih0    = (const float*)d_in[8];
    const float* Whh0    = (const float*)d_in[9];
    const float* bih0    = (const float*)d_in[10];
    const float* bhh0    = (const float*)d_in[11];
    const float* Wih1    = (const float*)d_in[12];
    const float* Whh1    = (const float*)d_in[13];
    const float* bih1    = (const float*)d_in[14];
    const float* bhh1    = (const float*)d_in[15];
    const float* W_out   = (const float*)d_in[16];
    const float* b_out   = (const float*)d_in[17];
    float* out = (float*)d_out;

    char* base = (char*)d_ws;
    size_t off = 0;
    auto alloc = [&](size_t bytes) -> char* {
        char* p = base + off;
        off += (bytes + 255) & ~(size_t)255;
        return p;
    };
    unsigned* barGen   = (unsigned*)alloc(256);
    unsigned* barFlags = (unsigned*)alloc(NBLK_ * 16 * 4);
    float* c0  = (float*)alloc((size_t)B_ * D_ * 4);
    float* c1  = (float*)alloc((size_t)B_ * D_ * 4);
    short* H1B = (short*)alloc((size_t)B_ * D_ * 2);
    short* X0a = (short*)alloc((size_t)B_ * 512 * 2);
    short* X1a = (short*)alloc((size_t)B_ * 512 * 2);
    size_t zeroBytes = off;
    short* X0b = (short*)alloc((size_t)B_ * 512 * 2);
    short* X1b = (short*)alloc((size_t)B_ * 512 * 2);
    short* appliedB = (short*)alloc((size_t)B_ * E_ * 2);
    float* awE   = (float*)alloc((size_t)T_ * B_ * L_ * 4);
    float* combE = (float*)alloc((size_t)T_ * B_ * D_ * 4);
    short* embB  = (short*)alloc((size_t)T_ * B_ * D_ * 2);
    short* WaEB  = (short*)alloc((size_t)L_ * D_ * 2);
    short* WaHB  = (short*)alloc((size_t)L_ * D_ * 2);
    short* WcEB  = (short*)alloc((size_t)D_ * D_ * 2);
    short* WcAB  = (short*)alloc((size_t)D_ * E_ * 2);
    short* Wg0B  = (short*)alloc((size_t)1024 * 512 * 2);
    short* Wg1B  = (short*)alloc((size_t)1024 * 512 * 2);
    short* WoutB = (short*)alloc((size_t)D_ * E_ * 2);
    float* bg0 = (float*)alloc(1024 * 4);
    float* bg1 = (float*)alloc(1024 * 4);
    short* encB = (short*)alloc((size_t)B_ * L_ * E_ * 2);
    int useEnc = (off <= ws_size) ? 1 : 0;

    zero_k<<<2048, 256, 0, stream>>>((unsigned*)base, zeroBytes / 4);
    if (useEnc)
        f2b4_k<<<4096, 256, 0, stream>>>(encF, encB, (size_t)B_ * L_ * E_ / 4);
    f2b4_k<<<64, 256, 0, stream>>>(W_out, WoutB, (size_t)D_ * E_ / 4);
    split_k<<<(80 * 512) / 256, 256, 0, stream>>>(W_attn, WaEB, WaHB, 80);
    split_k<<<(256 * 512) / 256, 256, 0, stream>>>(W_comb, WcEB, WcAB, 256);
    gatesW_k<<<2048, 256, 0, stream>>>(Wih0, Whh0, bih0, bhh0, Wg0B, bg0);
    gatesW_k<<<2048, 256, 0, stream>>>(Wih1, Whh1, bih1, bhh1, Wg1B, bg1);
    embed_k<<<(T_ * B_ * D_) / 256, 256, 0, stream>>>(tsi, commonE, syms, embB);
    gemm_k<<<dim3(320, 2), 256, 0, stream>>>(embB, 256, WaEB, awE, 80, 20480, 80, 256);
    gemm_k<<<dim3(320, 4), 256, 0, stream>>>(embB, 256, WcEB, combE, 256, 20480, 256, 256);

    DecArgs da;
    da.encB = encB; da.encF = encF; da.useEnc = useEnc;
    da.WaHB = WaHB; da.awE = awE; da.b_attn = b_attn;
    da.WcAB = WcAB; da.combE = combE; da.b_comb = b_comb;
    da.Wg0B = Wg0B; da.bg0 = bg0;
    da.Wg1B = Wg1B; da.bg1 = bg1;
    da.WoutB = WoutB; da.b_out = b_out;
    da.c0 = c0; da.c1 = c1; da.H1B = H1B;
    da.X0a = X0a; da.X0b = X0b; da.X1a = X1a; da.X1b = X1b;
    da.appliedB = appliedB;
    da.barFlags = barFlags; da.barGen = barGen;
    da.out = out;
    (void)hipFuncSetAttribute((const void*)decode_k,
                              hipFuncAttributeMaxDynamicSharedMemorySize, SMEM_SZ);
    decode_k<<<NBLK_, 256, SMEM_SZ, stream>>>(da);
}